// Round 11
// baseline (214.803 us; speedup 1.0000x reference)
//
#include <hip/hip_runtime.h>

typedef unsigned short u16;
typedef __bf16 bf16x8 __attribute__((ext_vector_type(8)));
typedef float f32x4 __attribute__((ext_vector_type(4)));

#define BATCH 2
#define NSEQ  2048
#define DIMN  1024
#define NH    16
#define DH    64
#define M_    (BATCH * NSEQ)   // 4096 rows of x
#define E_    (3 * DIMN)       // 3072 qkv features
#define K_    DIMN             // 1024 reduction dim
#define QKV_BYTES ((size_t)M_ * E_ * sizeof(u16))
#define XB_ELEMS  ((size_t)M_ * K_)
#define WB_ELEMS  ((size_t)E_ * K_)
#define NEED2     (QKV_BYTES + (XB_ELEMS + WB_ELEMS) * sizeof(u16))  // 39.8 MB

__device__ __forceinline__ u16 f2bf(float f) {
  union { float f; unsigned u; } v; v.f = f;
  unsigned r = v.u + 0x7fffu + ((v.u >> 16) & 1u);
  return (u16)(r >> 16);
}
__device__ __forceinline__ uint4 pack8(const float4 a, const float4 b) {
  union { u16 h[8]; uint4 q; } p;
  p.h[0] = f2bf(a.x); p.h[1] = f2bf(a.y); p.h[2] = f2bf(a.z); p.h[3] = f2bf(a.w);
  p.h[4] = f2bf(b.x); p.h[5] = f2bf(b.y); p.h[6] = f2bf(b.z); p.h[7] = f2bf(b.w);
  return p.q;
}
__device__ __forceinline__ void async16(const void* g, void* lds) {
  __builtin_amdgcn_global_load_lds(
      (const __attribute__((address_space(1))) void*)g,
      (__attribute__((address_space(3))) void*)lds, 16, 0, 0);
}

// ---------------------------------------------------------------------------
// Kernel 0: one-shot fp32 -> bf16 convert of X and W (memory-bound, ~7 us).
// ---------------------------------------------------------------------------
__global__ __launch_bounds__(256, 4)
void convert_bf16(const float* __restrict__ X, const float* __restrict__ W,
                  u16* __restrict__ Xb, u16* __restrict__ Wb) {
  const size_t nx = XB_ELEMS / 8, nw = WB_ELEMS / 8;
  const size_t stride = (size_t)gridDim.x * blockDim.x;
  for (size_t i = blockIdx.x * blockDim.x + threadIdx.x; i < nx; i += stride) {
    const float4 a = *(const float4*)&X[i * 8];
    const float4 b = *(const float4*)&X[i * 8 + 4];
    *(uint4*)&Xb[i * 8] = pack8(a, b);
  }
  for (size_t i = blockIdx.x * blockDim.x + threadIdx.x; i < nw; i += stride) {
    const float4 a = *(const float4*)&W[i * 8];
    const float4 b = *(const float4*)&W[i * 8 + 4];
    *(uint4*)&Wb[i * 8] = pack8(a, b);
  }
}

// ---------------------------------------------------------------------------
// Kernel 1: r9-EXACT GEMM (best measured: 173.65 total). 128x128 tile, BK=64,
// global_load_lds staging, XCD-bijective swizzle, (256,3). GEMM is CLOSED:
// r8 dbuf regressed (m132 occupancy cut), r9 (256,3) neutral, r10 256^2 tile
// regressed (VGPR-cap spills + 192<256 CU undersubscription; traffic model
// also disproven -- ~210MB L3 traffic = 2.7 TB/s, far under ceiling). The
// structure sits on its documented shape curve (m102: ~320 TF @ this scale).
// ---------------------------------------------------------------------------
__global__ __launch_bounds__(256, 3)
void qkv_gemm_a(const u16* __restrict__ Xb, const u16* __restrict__ Wb,
                u16* __restrict__ QKV) {
  __shared__ __align__(16) u16 As[128 * 64];
  __shared__ __align__(16) u16 Bs[128 * 64];
  const int tid  = threadIdx.x;
  const int wave = tid >> 6, lane = tid & 63;
  const int lin = blockIdx.y * gridDim.x + blockIdx.x;   // 0..767
  const int nl  = (lin & 7) * 96 + (lin >> 3);           // bijective (768%8==0)
  const int m0 = (nl & 31) * 128;                        // gridDim.x == 32
  const int n0 = (nl >> 5) * 128;
  const int wm = (wave >> 1) * 64;
  const int wn = (wave & 1) * 64;
  const int lcol = lane & 15, lrow = lane >> 4;
  const int lr8 = lane >> 3;
  const int slog = (lane & 7) ^ lr8;

  f32x4 acc[4][4] = {};

  for (int k0 = 0; k0 < K_; k0 += 64) {
    __syncthreads();
    #pragma unroll
    for (int i = 0; i < 4; ++i) {
      const int g = wave * 4 + i;
      const int r = g * 8 + lr8;
      async16(Xb + (size_t)(m0 + r) * K_ + k0 + slog * 8, &As[g * 512]);
      async16(Wb + (size_t)(n0 + r) * K_ + k0 + slog * 8, &Bs[g * 512]);
    }
    __syncthreads();
    #pragma unroll
    for (int ks = 0; ks < 64; ks += 32) {
      const int segl = (ks >> 3) + lrow;
      bf16x8 af[4], bfr[4];
      #pragma unroll
      for (int i = 0; i < 4; ++i) {
        const int r = wm + lcol + 16 * i;
        af[i] = *(const bf16x8*)&As[r * 64 + ((segl ^ (r & 7)) * 8)];
      }
      #pragma unroll
      for (int j = 0; j < 4; ++j) {
        const int r = wn + lcol + 16 * j;
        bfr[j] = *(const bf16x8*)&Bs[r * 64 + ((segl ^ (r & 7)) * 8)];
      }
      #pragma unroll
      for (int i = 0; i < 4; ++i)
        #pragma unroll
        for (int j = 0; j < 4; ++j)
          acc[i][j] = __builtin_amdgcn_mfma_f32_16x16x32_bf16(
              af[i], bfr[j], acc[i][j], 0, 0, 0);
    }
  }

  #pragma unroll
  for (int i = 0; i < 4; ++i)
    #pragma unroll
    for (int j = 0; j < 4; ++j)
      #pragma unroll
      for (int r = 0; r < 4; ++r) {
        const int gm = m0 + wm + 16 * i + lrow * 4 + r;
        const int gn = n0 + wn + 16 * j + lcol;
        QKV[(size_t)gm * E_ + gn] = f2bf(acc[i][j][r]);
      }
}

// Fallback GEMM (fused fp32->bf16 staging) if ws too small for Xb/Wb.
__global__ __launch_bounds__(256, 2)
void qkv_gemm_f(const float* __restrict__ X, const float* __restrict__ W,
                u16* __restrict__ QKV) {
  __shared__ __align__(16) u16 As[128 * 64];
  __shared__ __align__(16) u16 Bs[128 * 64];
  const int tid  = threadIdx.x;
  const int wave = tid >> 6, lane = tid & 63;
  const int m0 = blockIdx.x * 128, n0 = blockIdx.y * 128;
  const int wm = (wave >> 1) * 64, wn = (wave & 1) * 64;
  const int lcol = lane & 15, lrow = lane >> 4;
  f32x4 acc[4][4] = {};
  for (int k0 = 0; k0 < K_; k0 += 64) {
    __syncthreads();
    #pragma unroll
    for (int p = 0; p < 4; ++p) {
      const int linear = p * 256 + tid;
      const int r = linear >> 3, s = linear & 7;
      const float4 a0 = *(const float4*)&X[(size_t)(m0 + r) * K_ + k0 + s * 8];
      const float4 a1 = *(const float4*)&X[(size_t)(m0 + r) * K_ + k0 + s * 8 + 4];
      const float4 b0 = *(const float4*)&W[(size_t)(n0 + r) * K_ + k0 + s * 8];
      const float4 b1 = *(const float4*)&W[(size_t)(n0 + r) * K_ + k0 + s * 8 + 4];
      const int ph = (s ^ (r & 7)) * 8;
      *(uint4*)&As[r * 64 + ph] = pack8(a0, a1);
      *(uint4*)&Bs[r * 64 + ph] = pack8(b0, b1);
    }
    __syncthreads();
    #pragma unroll
    for (int ks = 0; ks < 64; ks += 32) {
      const int segl = (ks >> 3) + lrow;
      bf16x8 af[4], bfr[4];
      #pragma unroll
      for (int i = 0; i < 4; ++i) {
        const int r = wm + lcol + 16 * i;
        af[i] = *(const bf16x8*)&As[r * 64 + ((segl ^ (r & 7)) * 8)];
      }
      #pragma unroll
      for (int j = 0; j < 4; ++j) {
        const int r = wn + lcol + 16 * j;
        bfr[j] = *(const bf16x8*)&Bs[r * 64 + ((segl ^ (r & 7)) * 8)];
      }
      #pragma unroll
      for (int i = 0; i < 4; ++i)
        #pragma unroll
        for (int j = 0; j < 4; ++j)
          acc[i][j] = __builtin_amdgcn_mfma_f32_16x16x32_bf16(
              af[i], bfr[j], acc[i][j], 0, 0, 0);
    }
  }
  #pragma unroll
  for (int i = 0; i < 4; ++i)
    #pragma unroll
    for (int j = 0; j < 4; ++j)
      #pragma unroll
      for (int r = 0; r < 4; ++r) {
        const int gm = m0 + wm + 16 * i + lrow * 4 + r;
        const int gn = n0 + wn + 16 * j + lcol;
        QKV[(size_t)gm * E_ + gn] = f2bf(acc[i][j][r]);
      }
}

// ---------------------------------------------------------------------------
// Kernel 2 (r11): r5-EXACT attention body, AMORTIZED 2x -- each block now
// covers 256 q-rows (wave: 64 = 2 q-tiles of the unchanged 32-row layout).
// Every LDS access pattern (Ks write/read, Vt scatter/read, Ps write/read,
// XOR keys, strides) is byte-identical to the frozen r5 kernel; the K/V tile
// and its staging are simply SHARED by twice the consumers:
//   - staging insts per unit work: 18 -> 9
//   - bk/bv ds_read_b128 per unit: each read now feeds 4 MFMAs (was 2)
//   => 70 -> 53 LDS insts/unit (-24%, ~-30% cyc) on the measured LDS-issue
//      bound (r1: 2x occupancy gave 0 gain => TLP halving to 4 waves/CU is
//      safe; r10 lesson: (256,1) so no VGPR cap, grid 256 = 1/CU balanced).
// Secondary: K/V global re-reads halve (FETCH 14.3 -> ~11 MB).
// ---------------------------------------------------------------------------
__global__ __launch_bounds__(256, 1)
void attn(const u16* __restrict__ QKV, float* __restrict__ Out) {
  __shared__ __align__(16) u16 Ks[64 * 72];
  __shared__ __align__(16) u16 Vt[64 * 72];        // XOR-swizzled, stride 72
  __shared__ __align__(16) u16 Ps[4][64 * 72];     // 64 q-rows per wave

  const int tid = threadIdx.x, wave = tid >> 6, lane = tid & 63;
  const int b = blockIdx.x >> 4, h = blockIdx.x & 15;
  const int i0 = blockIdx.y * 256;
  const int lcol = lane & 15, lrow = lane >> 4;
  const size_t base = (size_t)b * NSEQ;
  const int qoff = h * DH, koff = DIMN + h * DH, voff = 2 * DIMN + h * DH;
  const int sr = tid >> 3;  // 0..31
  const int sg = tid & 7;

  bf16x8 ones;
  #pragma unroll
  for (int t = 0; t < 8; ++t) ones[t] = (__bf16)1.0f;

  // Q fragments straight from global (once): 2 q-tiles per wave
  bf16x8 aq[2][2][2];   // [qt][qi][ksi]
  #pragma unroll
  for (int qt = 0; qt < 2; ++qt)
    #pragma unroll
    for (int qi = 0; qi < 2; ++qi)
      #pragma unroll
      for (int ksi = 0; ksi < 2; ++ksi) {
        const int row = i0 + wave * 64 + qt * 32 + qi * 16 + lcol;
        aq[qt][qi][ksi] = *(const bf16x8*)&QKV[(base + row) * E_ + qoff +
                                               (ksi * 4 + lrow) * 8];
      }

  // prefetch K/V tile 0 (unchanged)
  uint4 kreg[2], vreg[2];
  #pragma unroll
  for (int p = 0; p < 2; ++p) {
    const int row = p * 32 + sr;
    const u16* src = &QKV[(base + row) * E_];
    kreg[p] = *(const uint4*)&src[koff + sg * 8];
    vreg[p] = *(const uint4*)&src[voff + sg * 8];
  }

  f32x4 o[2][2][4] = {};
  f32x4 lacc[2][2] = {};

  for (int j0 = 0; j0 < NSEQ; j0 += 64) {
    __syncthreads();
    #pragma unroll
    for (int p = 0; p < 2; ++p) {
      const int row = p * 32 + sr;
      *(uint4*)&Ks[row * 72 + sg * 8] = kreg[p];
      const u16* pv = (const u16*)&vreg[p];
      const int jseg = (row >> 3) & 7, jlo = row & 7;
      #pragma unroll
      for (int t = 0; t < 8; ++t)
        Vt[(sg * 8 + t) * 72 + (((jseg ^ sg) & 7) * 8 + jlo)] = pv[t];
    }
    __syncthreads();

    if (j0 + 64 < NSEQ) {
      #pragma unroll
      for (int p = 0; p < 2; ++p) {
        const int row = p * 32 + sr;
        const u16* src = &QKV[(base + j0 + 64 + row) * E_];
        kreg[p] = *(const uint4*)&src[koff + sg * 8];
        vreg[p] = *(const uint4*)&src[voff + sg * 8];
      }
    }

    // S: each bk read feeds 4 MFMAs (2 qt x 2 qi)
    f32x4 s[2][2][4] = {};
    #pragma unroll
    for (int ksi = 0; ksi < 2; ++ksi) {
      const int seg = ksi * 4 + lrow;
      #pragma unroll
      for (int jt = 0; jt < 4; ++jt) {
        const bf16x8 bk = *(const bf16x8*)&Ks[(jt * 16 + lcol) * 72 + seg * 8];
        __builtin_amdgcn_s_setprio(1);
        #pragma unroll
        for (int qt = 0; qt < 2; ++qt)
          #pragma unroll
          for (int qi = 0; qi < 2; ++qi)
            s[qt][qi][jt] = __builtin_amdgcn_mfma_f32_16x16x32_bf16(
                aq[qt][qi][ksi], bk, s[qt][qi][jt], 0, 0, 0);
        __builtin_amdgcn_s_setprio(0);
      }
    }

    // static-base softmax numerator -> Ps (A-layout, pattern unchanged)
    #pragma unroll
    for (int qt = 0; qt < 2; ++qt)
      #pragma unroll
      for (int qi = 0; qi < 2; ++qi)
        #pragma unroll
        for (int jt = 0; jt < 4; ++jt)
          #pragma unroll
          for (int r = 0; r < 4; ++r) {
            const float p = __expf(fmaf(s[qt][qi][jt][r], 0.125f, -12.0f));
            Ps[wave][(qt * 32 + qi * 16 + lrow * 4 + r) * 72 + jt * 16 + lcol] =
                f2bf(p);
          }

    // O += P@V ; l += P@1 — each bv read feeds 4 MFMAs
    #pragma unroll
    for (int ksi = 0; ksi < 2; ++ksi) {
      const int seg = ksi * 4 + lrow;
      bf16x8 ap[2][2];
      #pragma unroll
      for (int qt = 0; qt < 2; ++qt)
        #pragma unroll
        for (int qi = 0; qi < 2; ++qi)
          ap[qt][qi] = *(const bf16x8*)
              &Ps[wave][(qt * 32 + qi * 16 + lcol) * 72 + seg * 8];
      __builtin_amdgcn_s_setprio(1);
      #pragma unroll
      for (int dt = 0; dt < 4; ++dt) {
        const int d = dt * 16 + lcol;
        const bf16x8 bv = *(const bf16x8*)&Vt[d * 72 + (((seg ^ (d >> 3)) & 7) * 8)];
        #pragma unroll
        for (int qt = 0; qt < 2; ++qt)
          #pragma unroll
          for (int qi = 0; qi < 2; ++qi)
            o[qt][qi][dt] = __builtin_amdgcn_mfma_f32_16x16x32_bf16(
                ap[qt][qi], bv, o[qt][qi][dt], 0, 0, 0);
      }
      #pragma unroll
      for (int qt = 0; qt < 2; ++qt)
        #pragma unroll
        for (int qi = 0; qi < 2; ++qi)
          lacc[qt][qi] = __builtin_amdgcn_mfma_f32_16x16x32_bf16(
              ap[qt][qi], ones, lacc[qt][qi], 0, 0, 0);
      __builtin_amdgcn_s_setprio(0);
    }
  }

  // epilogue: FP32 out[b, n*H + h, d] = o / l
  #pragma unroll
  for (int qt = 0; qt < 2; ++qt)
    #pragma unroll
    for (int qi = 0; qi < 2; ++qi)
      #pragma unroll
      for (int r = 0; r < 4; ++r) {
        const float inv = 1.0f / lacc[qt][qi][r];
        const int i = i0 + wave * 64 + qt * 32 + qi * 16 + lrow * 4 + r;
        #pragma unroll
        for (int dt = 0; dt < 4; ++dt) {
          const int d = dt * 16 + lcol;
          Out[((base + i) * NH + h) * DH + d] = o[qt][qi][dt][r] * inv;
        }
      }
}

extern "C" void kernel_launch(void* const* d_in, const int* in_sizes, int n_in,
                              void* d_out, int out_size, void* d_ws, size_t ws_size,
                              hipStream_t stream) {
  const float* x = (const float*)d_in[0];   // fp32 (2,2048,1024)
  const float* w = (const float*)d_in[1];   // fp32 (3072,1024)
  u16* qkv = (u16*)d_ws;                    // bf16 scratch (24 MB)
  float* out = (float*)d_out;               // fp32 (2, 2048*16, 64)

  if (ws_size < QKV_BYTES) return;

  if (ws_size >= NEED2) {
    u16* Xb = (u16*)((char*)d_ws + QKV_BYTES);
    u16* Wb = Xb + XB_ELEMS;
    convert_bf16<<<1024, 256, 0, stream>>>(x, w, Xb, Wb);
    qkv_gemm_a<<<dim3(M_ / 128, E_ / 128), 256, 0, stream>>>(Xb, Wb, qkv);
  } else {
    qkv_gemm_f<<<dim3(M_ / 128, E_ / 128), 256, 0, stream>>>(x, w, qkv);
  }
  attn<<<dim3(BATCH * NH, NSEQ / 256), 256, 0, stream>>>(qkv, out);
}

// Round 12
// 176.469 us; speedup vs baseline: 1.2172x; 1.2172x over previous
//
#include <hip/hip_runtime.h>

typedef unsigned short u16;
typedef __bf16 bf16x8 __attribute__((ext_vector_type(8)));
typedef float f32x4 __attribute__((ext_vector_type(4)));

#define BATCH 2
#define NSEQ  2048
#define DIMN  1024
#define NH    16
#define DH    64
#define M_    (BATCH * NSEQ)   // 4096 rows of x
#define E_    (3 * DIMN)       // 3072 qkv features
#define K_    DIMN             // 1024 reduction dim
#define QKV_BYTES ((size_t)M_ * E_ * sizeof(u16))
#define XB_ELEMS  ((size_t)M_ * K_)
#define WB_ELEMS  ((size_t)E_ * K_)
#define NEED2     (QKV_BYTES + (XB_ELEMS + WB_ELEMS) * sizeof(u16))  // 39.8 MB

__device__ __forceinline__ u16 f2bf(float f) {
  union { float f; unsigned u; } v; v.f = f;
  unsigned r = v.u + 0x7fffu + ((v.u >> 16) & 1u);
  return (u16)(r >> 16);
}
__device__ __forceinline__ uint4 pack8(const float4 a, const float4 b) {
  union { u16 h[8]; uint4 q; } p;
  p.h[0] = f2bf(a.x); p.h[1] = f2bf(a.y); p.h[2] = f2bf(a.z); p.h[3] = f2bf(a.w);
  p.h[4] = f2bf(b.x); p.h[5] = f2bf(b.y); p.h[6] = f2bf(b.z); p.h[7] = f2bf(b.w);
  return p.q;
}
__device__ __forceinline__ void async16(const void* g, void* lds) {
  __builtin_amdgcn_global_load_lds(
      (const __attribute__((address_space(1))) void*)g,
      (__attribute__((address_space(3))) void*)lds, 16, 0, 0);
}

// ---------------------------------------------------------------------------
// Kernel 0: one-shot fp32 -> bf16 convert of X and W (memory-bound, ~7 us).
// ---------------------------------------------------------------------------
__global__ __launch_bounds__(256, 4)
void convert_bf16(const float* __restrict__ X, const float* __restrict__ W,
                  u16* __restrict__ Xb, u16* __restrict__ Wb) {
  const size_t nx = XB_ELEMS / 8, nw = WB_ELEMS / 8;
  const size_t stride = (size_t)gridDim.x * blockDim.x;
  for (size_t i = blockIdx.x * blockDim.x + threadIdx.x; i < nx; i += stride) {
    const float4 a = *(const float4*)&X[i * 8];
    const float4 b = *(const float4*)&X[i * 8 + 4];
    *(uint4*)&Xb[i * 8] = pack8(a, b);
  }
  for (size_t i = blockIdx.x * blockDim.x + threadIdx.x; i < nw; i += stride) {
    const float4 a = *(const float4*)&W[i * 8];
    const float4 b = *(const float4*)&W[i * 8 + 4];
    *(uint4*)&Wb[i * 8] = pack8(a, b);
  }
}

// ---------------------------------------------------------------------------
// Kernel 1: r9-EXACT GEMM (best measured: 173.65 total). 128x128 tile, BK=64,
// global_load_lds staging, XCD-bijective swizzle, (256,3). GEMM is CLOSED.
// ---------------------------------------------------------------------------
__global__ __launch_bounds__(256, 3)
void qkv_gemm_a(const u16* __restrict__ Xb, const u16* __restrict__ Wb,
                u16* __restrict__ QKV) {
  __shared__ __align__(16) u16 As[128 * 64];
  __shared__ __align__(16) u16 Bs[128 * 64];
  const int tid  = threadIdx.x;
  const int wave = tid >> 6, lane = tid & 63;
  const int lin = blockIdx.y * gridDim.x + blockIdx.x;   // 0..767
  const int nl  = (lin & 7) * 96 + (lin >> 3);           // bijective (768%8==0)
  const int m0 = (nl & 31) * 128;                        // gridDim.x == 32
  const int n0 = (nl >> 5) * 128;
  const int wm = (wave >> 1) * 64;
  const int wn = (wave & 1) * 64;
  const int lcol = lane & 15, lrow = lane >> 4;
  const int lr8 = lane >> 3;
  const int slog = (lane & 7) ^ lr8;

  f32x4 acc[4][4] = {};

  for (int k0 = 0; k0 < K_; k0 += 64) {
    __syncthreads();
    #pragma unroll
    for (int i = 0; i < 4; ++i) {
      const int g = wave * 4 + i;
      const int r = g * 8 + lr8;
      async16(Xb + (size_t)(m0 + r) * K_ + k0 + slog * 8, &As[g * 512]);
      async16(Wb + (size_t)(n0 + r) * K_ + k0 + slog * 8, &Bs[g * 512]);
    }
    __syncthreads();
    #pragma unroll
    for (int ks = 0; ks < 64; ks += 32) {
      const int segl = (ks >> 3) + lrow;
      bf16x8 af[4], bfr[4];
      #pragma unroll
      for (int i = 0; i < 4; ++i) {
        const int r = wm + lcol + 16 * i;
        af[i] = *(const bf16x8*)&As[r * 64 + ((segl ^ (r & 7)) * 8)];
      }
      #pragma unroll
      for (int j = 0; j < 4; ++j) {
        const int r = wn + lcol + 16 * j;
        bfr[j] = *(const bf16x8*)&Bs[r * 64 + ((segl ^ (r & 7)) * 8)];
      }
      #pragma unroll
      for (int i = 0; i < 4; ++i)
        #pragma unroll
        for (int j = 0; j < 4; ++j)
          acc[i][j] = __builtin_amdgcn_mfma_f32_16x16x32_bf16(
              af[i], bfr[j], acc[i][j], 0, 0, 0);
    }
  }

  #pragma unroll
  for (int i = 0; i < 4; ++i)
    #pragma unroll
    for (int j = 0; j < 4; ++j)
      #pragma unroll
      for (int r = 0; r < 4; ++r) {
        const int gm = m0 + wm + 16 * i + lrow * 4 + r;
        const int gn = n0 + wn + 16 * j + lcol;
        QKV[(size_t)gm * E_ + gn] = f2bf(acc[i][j][r]);
      }
}

// Fallback GEMM (fused fp32->bf16 staging) if ws too small for Xb/Wb.
__global__ __launch_bounds__(256, 2)
void qkv_gemm_f(const float* __restrict__ X, const float* __restrict__ W,
                u16* __restrict__ QKV) {
  __shared__ __align__(16) u16 As[128 * 64];
  __shared__ __align__(16) u16 Bs[128 * 64];
  const int tid  = threadIdx.x;
  const int wave = tid >> 6, lane = tid & 63;
  const int m0 = blockIdx.x * 128, n0 = blockIdx.y * 128;
  const int wm = (wave >> 1) * 64, wn = (wave & 1) * 64;
  const int lcol = lane & 15, lrow = lane >> 4;
  f32x4 acc[4][4] = {};
  for (int k0 = 0; k0 < K_; k0 += 64) {
    __syncthreads();
    #pragma unroll
    for (int p = 0; p < 4; ++p) {
      const int linear = p * 256 + tid;
      const int r = linear >> 3, s = linear & 7;
      const float4 a0 = *(const float4*)&X[(size_t)(m0 + r) * K_ + k0 + s * 8];
      const float4 a1 = *(const float4*)&X[(size_t)(m0 + r) * K_ + k0 + s * 8 + 4];
      const float4 b0 = *(const float4*)&W[(size_t)(n0 + r) * K_ + k0 + s * 8];
      const float4 b1 = *(const float4*)&W[(size_t)(n0 + r) * K_ + k0 + s * 8 + 4];
      const int ph = (s ^ (r & 7)) * 8;
      *(uint4*)&As[r * 64 + ph] = pack8(a0, a1);
      *(uint4*)&Bs[r * 64 + ph] = pack8(b0, b1);
    }
    __syncthreads();
    #pragma unroll
    for (int ks = 0; ks < 64; ks += 32) {
      const int segl = (ks >> 3) + lrow;
      bf16x8 af[4], bfr[4];
      #pragma unroll
      for (int i = 0; i < 4; ++i) {
        const int r = wm + lcol + 16 * i;
        af[i] = *(const bf16x8*)&As[r * 64 + ((segl ^ (r & 7)) * 8)];
      }
      #pragma unroll
      for (int j = 0; j < 4; ++j) {
        const int r = wn + lcol + 16 * j;
        bfr[j] = *(const bf16x8*)&Bs[r * 64 + ((segl ^ (r & 7)) * 8)];
      }
      #pragma unroll
      for (int i = 0; i < 4; ++i)
        #pragma unroll
        for (int j = 0; j < 4; ++j)
          acc[i][j] = __builtin_amdgcn_mfma_f32_16x16x32_bf16(
              af[i], bfr[j], acc[i][j], 0, 0, 0);
    }
  }
  #pragma unroll
  for (int i = 0; i < 4; ++i)
    #pragma unroll
    for (int j = 0; j < 4; ++j)
      #pragma unroll
      for (int r = 0; r < 4; ++r) {
        const int gm = m0 + wm + 16 * i + lrow * 4 + r;
        const int gn = n0 + wn + 16 * j + lcol;
        QKV[(size_t)gm * E_ + gn] = f2bf(acc[i][j][r]);
      }
}

// ---------------------------------------------------------------------------
// Kernel 2 (r12): r5 attention body with KVBLK 64 -> 128 (barrier halving).
// r11 lesson: 8 waves/CU is REQUIRED (4 waves/CU = 1/SIMD doubled time), and
// 8 waves/CU forces 32 q-rows/wave (65536 total rows) -> amortization closed.
// This keeps 32 q-rows/wave + 8 waves/CU and halves the ITERATION count:
// 16 j-iters instead of 32 -> half the __syncthreads (32) and half the
// prefetch branches. All per-instruction patterns preserved:
//   - Ks stride stays 72; Vt/Ps strides 72 -> 136 u16 = 68 dw == 4 mod 32,
//     the SAME bank rotation as 36 dw -> conflict structure identical.
//   - Vt XOR scatter gains one bit: write col += (row & 64); read col +=
//     (seg & 8) << 3. Verified consistent write/read.
// Per-iter work exactly doubles; totals (MFMA, exp, LDS insts) unchanged.
// LDS 70.7 KB -> 2 blocks/CU = 8 waves/CU (unchanged).
// ---------------------------------------------------------------------------
__global__ __launch_bounds__(256, 2)
void attn(const u16* __restrict__ QKV, float* __restrict__ Out) {
  __shared__ __align__(16) u16 Ks[128 * 72];       // rows j(128), cols k+pad
  __shared__ __align__(16) u16 Vt[64 * 136];       // rows d(64), cols j(128)+pad
  __shared__ __align__(16) u16 Ps[4][32 * 136];    // per-wave [q][j(128)]+pad

  const int tid = threadIdx.x, wave = tid >> 6, lane = tid & 63;
  const int b = blockIdx.x >> 4, h = blockIdx.x & 15;
  const int i0 = blockIdx.y * 128;
  const int lcol = lane & 15, lrow = lane >> 4;
  const size_t base = (size_t)b * NSEQ;
  const int qoff = h * DH, koff = DIMN + h * DH, voff = 2 * DIMN + h * DH;
  const int sr = tid >> 3;  // 0..31
  const int sg = tid & 7;

  bf16x8 ones;
  #pragma unroll
  for (int t = 0; t < 8; ++t) ones[t] = (__bf16)1.0f;

  // Q fragments straight from global (once)
  bf16x8 aq[2][2];
  #pragma unroll
  for (int qi = 0; qi < 2; ++qi)
    #pragma unroll
    for (int ksi = 0; ksi < 2; ++ksi) {
      const int row = i0 + wave * 32 + qi * 16 + lcol;
      aq[qi][ksi] = *(const bf16x8*)&QKV[(base + row) * E_ + qoff +
                                         (ksi * 4 + lrow) * 8];
    }

  // prefetch K/V tile 0: 4 row-groups of 32 (j = 0..127)
  uint4 kreg[4], vreg[4];
  #pragma unroll
  for (int p = 0; p < 4; ++p) {
    const int row = p * 32 + sr;
    const u16* src = &QKV[(base + row) * E_];
    kreg[p] = *(const uint4*)&src[koff + sg * 8];
    vreg[p] = *(const uint4*)&src[voff + sg * 8];
  }

  f32x4 o[2][4] = {};
  f32x4 lacc[2] = {};

  for (int j0 = 0; j0 < NSEQ; j0 += 128) {
    __syncthreads();
    #pragma unroll
    for (int p = 0; p < 4; ++p) {
      const int row = p * 32 + sr;                 // j within tile, 0..127
      *(uint4*)&Ks[row * 72 + sg * 8] = kreg[p];
      const u16* pv = (const u16*)&vreg[p];
      const int jseg = (row >> 3) & 7, jlo = row & 7, jhi = row & 64;
      #pragma unroll
      for (int t = 0; t < 8; ++t)
        Vt[(sg * 8 + t) * 136 + jhi + (((jseg ^ sg) & 7) * 8 + jlo)] = pv[t];
    }
    __syncthreads();

    if (j0 + 128 < NSEQ) {
      #pragma unroll
      for (int p = 0; p < 4; ++p) {
        const int row = p * 32 + sr;
        const u16* src = &QKV[(base + j0 + 128 + row) * E_];
        kreg[p] = *(const uint4*)&src[koff + sg * 8];
        vreg[p] = *(const uint4*)&src[voff + sg * 8];
      }
    }

    // S: [2 qi x 16 q] x 128 j — pattern identical, jt now 0..7
    f32x4 s[2][8] = {};
    #pragma unroll
    for (int ksi = 0; ksi < 2; ++ksi) {
      const int seg = ksi * 4 + lrow;
      #pragma unroll
      for (int jt = 0; jt < 8; ++jt) {
        const bf16x8 bk = *(const bf16x8*)&Ks[(jt * 16 + lcol) * 72 + seg * 8];
        __builtin_amdgcn_s_setprio(1);
        #pragma unroll
        for (int qi = 0; qi < 2; ++qi)
          s[qi][jt] = __builtin_amdgcn_mfma_f32_16x16x32_bf16(
              aq[qi][ksi], bk, s[qi][jt], 0, 0, 0);
        __builtin_amdgcn_s_setprio(0);
      }
    }

    // static-base softmax numerator -> Ps (A-layout, stride 136)
    #pragma unroll
    for (int qi = 0; qi < 2; ++qi)
      #pragma unroll
      for (int jt = 0; jt < 8; ++jt)
        #pragma unroll
        for (int r = 0; r < 4; ++r) {
          const float p = __expf(fmaf(s[qi][jt][r], 0.125f, -12.0f));
          Ps[wave][(qi * 16 + lrow * 4 + r) * 136 + jt * 16 + lcol] = f2bf(p);
        }

    // O += P@V ; l += P@1 — js spans 4 j-blocks of 32
    #pragma unroll
    for (int js = 0; js < 4; ++js) {
      const int seg = js * 4 + lrow;               // j-octet 0..15
      bf16x8 ap[2];
      #pragma unroll
      for (int qi = 0; qi < 2; ++qi)
        ap[qi] = *(const bf16x8*)&Ps[wave][(qi * 16 + lcol) * 136 + seg * 8];
      __builtin_amdgcn_s_setprio(1);
      #pragma unroll
      for (int dt = 0; dt < 4; ++dt) {
        const int d = dt * 16 + lcol;
        const bf16x8 bv = *(const bf16x8*)
            &Vt[d * 136 + ((seg & 8) << 3) + (((seg ^ (d >> 3)) & 7) * 8)];
        #pragma unroll
        for (int qi = 0; qi < 2; ++qi)
          o[qi][dt] = __builtin_amdgcn_mfma_f32_16x16x32_bf16(
              ap[qi], bv, o[qi][dt], 0, 0, 0);
      }
      #pragma unroll
      for (int qi = 0; qi < 2; ++qi)
        lacc[qi] = __builtin_amdgcn_mfma_f32_16x16x32_bf16(
            ap[qi], ones, lacc[qi], 0, 0, 0);
      __builtin_amdgcn_s_setprio(0);
    }
  }

  // epilogue: FP32 out[b, n*H + h, d] = o / l
  #pragma unroll
  for (int qi = 0; qi < 2; ++qi)
    #pragma unroll
    for (int r = 0; r < 4; ++r) {
      const float inv = 1.0f / lacc[qi][r];
      const int i = i0 + wave * 32 + qi * 16 + lrow * 4 + r;
      #pragma unroll
      for (int dt = 0; dt < 4; ++dt) {
        const int d = dt * 16 + lcol;
        Out[((base + i) * NH + h) * DH + d] = o[qi][dt][r] * inv;
      }
    }
}

extern "C" void kernel_launch(void* const* d_in, const int* in_sizes, int n_in,
                              void* d_out, int out_size, void* d_ws, size_t ws_size,
                              hipStream_t stream) {
  const float* x = (const float*)d_in[0];   // fp32 (2,2048,1024)
  const float* w = (const float*)d_in[1];   // fp32 (3072,1024)
  u16* qkv = (u16*)d_ws;                    // bf16 scratch (24 MB)
  float* out = (float*)d_out;               // fp32 (2, 2048*16, 64)

  if (ws_size < QKV_BYTES) return;

  if (ws_size >= NEED2) {
    u16* Xb = (u16*)((char*)d_ws + QKV_BYTES);
    u16* Wb = Xb + XB_ELEMS;
    convert_bf16<<<1024, 256, 0, stream>>>(x, w, Xb, Wb);
    qkv_gemm_a<<<dim3(M_ / 128, E_ / 128), 256, 0, stream>>>(Xb, Wb, qkv);
  } else {
    qkv_gemm_f<<<dim3(M_ / 128, E_ / 128), 256, 0, stream>>>(x, w, qkv);
  }
  attn<<<dim3(BATCH * NH, NSEQ / 128), 256, 0, stream>>>(qkv, out);
}

// Round 13
// 173.008 us; speedup vs baseline: 1.2416x; 1.0200x over previous
//
#include <hip/hip_runtime.h>

typedef unsigned short u16;
typedef __bf16 bf16x8 __attribute__((ext_vector_type(8)));
typedef float f32x4 __attribute__((ext_vector_type(4)));

#define BATCH 2
#define NSEQ  2048
#define DIMN  1024
#define NH    16
#define DH    64
#define M_    (BATCH * NSEQ)   // 4096 rows of x
#define E_    (3 * DIMN)       // 3072 qkv features
#define K_    DIMN             // 1024 reduction dim
#define QKV_BYTES ((size_t)M_ * E_ * sizeof(u16))
#define XB_ELEMS  ((size_t)M_ * K_)
#define WB_ELEMS  ((size_t)E_ * K_)
#define NEED2     (QKV_BYTES + (XB_ELEMS + WB_ELEMS) * sizeof(u16))  // 39.8 MB

__device__ __forceinline__ u16 f2bf(float f) {
  union { float f; unsigned u; } v; v.f = f;
  unsigned r = v.u + 0x7fffu + ((v.u >> 16) & 1u);
  return (u16)(r >> 16);
}
__device__ __forceinline__ uint4 pack8(const float4 a, const float4 b) {
  union { u16 h[8]; uint4 q; } p;
  p.h[0] = f2bf(a.x); p.h[1] = f2bf(a.y); p.h[2] = f2bf(a.z); p.h[3] = f2bf(a.w);
  p.h[4] = f2bf(b.x); p.h[5] = f2bf(b.y); p.h[6] = f2bf(b.z); p.h[7] = f2bf(b.w);
  return p.q;
}
__device__ __forceinline__ void async16(const void* g, void* lds) {
  __builtin_amdgcn_global_load_lds(
      (const __attribute__((address_space(1))) void*)g,
      (__attribute__((address_space(3))) void*)lds, 16, 0, 0);
}

// ---------------------------------------------------------------------------
// Kernel 0: one-shot fp32 -> bf16 convert of X and W (memory-bound, ~7 us).
// ---------------------------------------------------------------------------
__global__ __launch_bounds__(256, 4)
void convert_bf16(const float* __restrict__ X, const float* __restrict__ W,
                  u16* __restrict__ Xb, u16* __restrict__ Wb) {
  const size_t nx = XB_ELEMS / 8, nw = WB_ELEMS / 8;
  const size_t stride = (size_t)gridDim.x * blockDim.x;
  for (size_t i = blockIdx.x * blockDim.x + threadIdx.x; i < nx; i += stride) {
    const float4 a = *(const float4*)&X[i * 8];
    const float4 b = *(const float4*)&X[i * 8 + 4];
    *(uint4*)&Xb[i * 8] = pack8(a, b);
  }
  for (size_t i = blockIdx.x * blockDim.x + threadIdx.x; i < nw; i += stride) {
    const float4 a = *(const float4*)&W[i * 8];
    const float4 b = *(const float4*)&W[i * 8 + 4];
    *(uint4*)&Wb[i * 8] = pack8(a, b);
  }
}

// ---------------------------------------------------------------------------
// Kernel 1: r9-EXACT GEMM (best measured: 173.65 total). 128x128 tile, BK=64,
// global_load_lds staging, XCD-bijective swizzle, (256,3). GEMM is CLOSED:
// r8 dbuf regressed (occupancy cut), r9 (256,3) neutral, r10 256^2 regressed
// (VGPR-cap spills + 192<256 CU undersubscription). On its shape curve.
// ---------------------------------------------------------------------------
__global__ __launch_bounds__(256, 3)
void qkv_gemm_a(const u16* __restrict__ Xb, const u16* __restrict__ Wb,
                u16* __restrict__ QKV) {
  __shared__ __align__(16) u16 As[128 * 64];
  __shared__ __align__(16) u16 Bs[128 * 64];
  const int tid  = threadIdx.x;
  const int wave = tid >> 6, lane = tid & 63;
  const int lin = blockIdx.y * gridDim.x + blockIdx.x;   // 0..767
  const int nl  = (lin & 7) * 96 + (lin >> 3);           // bijective (768%8==0)
  const int m0 = (nl & 31) * 128;                        // gridDim.x == 32
  const int n0 = (nl >> 5) * 128;
  const int wm = (wave >> 1) * 64;
  const int wn = (wave & 1) * 64;
  const int lcol = lane & 15, lrow = lane >> 4;
  const int lr8 = lane >> 3;
  const int slog = (lane & 7) ^ lr8;

  f32x4 acc[4][4] = {};

  for (int k0 = 0; k0 < K_; k0 += 64) {
    __syncthreads();
    #pragma unroll
    for (int i = 0; i < 4; ++i) {
      const int g = wave * 4 + i;
      const int r = g * 8 + lr8;
      async16(Xb + (size_t)(m0 + r) * K_ + k0 + slog * 8, &As[g * 512]);
      async16(Wb + (size_t)(n0 + r) * K_ + k0 + slog * 8, &Bs[g * 512]);
    }
    __syncthreads();
    #pragma unroll
    for (int ks = 0; ks < 64; ks += 32) {
      const int segl = (ks >> 3) + lrow;
      bf16x8 af[4], bfr[4];
      #pragma unroll
      for (int i = 0; i < 4; ++i) {
        const int r = wm + lcol + 16 * i;
        af[i] = *(const bf16x8*)&As[r * 64 + ((segl ^ (r & 7)) * 8)];
      }
      #pragma unroll
      for (int j = 0; j < 4; ++j) {
        const int r = wn + lcol + 16 * j;
        bfr[j] = *(const bf16x8*)&Bs[r * 64 + ((segl ^ (r & 7)) * 8)];
      }
      #pragma unroll
      for (int i = 0; i < 4; ++i)
        #pragma unroll
        for (int j = 0; j < 4; ++j)
          acc[i][j] = __builtin_amdgcn_mfma_f32_16x16x32_bf16(
              af[i], bfr[j], acc[i][j], 0, 0, 0);
    }
  }

  #pragma unroll
  for (int i = 0; i < 4; ++i)
    #pragma unroll
    for (int j = 0; j < 4; ++j)
      #pragma unroll
      for (int r = 0; r < 4; ++r) {
        const int gm = m0 + wm + 16 * i + lrow * 4 + r;
        const int gn = n0 + wn + 16 * j + lcol;
        QKV[(size_t)gm * E_ + gn] = f2bf(acc[i][j][r]);
      }
}

// Fallback GEMM (fused fp32->bf16 staging) if ws too small for Xb/Wb.
__global__ __launch_bounds__(256, 2)
void qkv_gemm_f(const float* __restrict__ X, const float* __restrict__ W,
                u16* __restrict__ QKV) {
  __shared__ __align__(16) u16 As[128 * 64];
  __shared__ __align__(16) u16 Bs[128 * 64];
  const int tid  = threadIdx.x;
  const int wave = tid >> 6, lane = tid & 63;
  const int m0 = blockIdx.x * 128, n0 = blockIdx.y * 128;
  const int wm = (wave >> 1) * 64, wn = (wave & 1) * 64;
  const int lcol = lane & 15, lrow = lane >> 4;
  f32x4 acc[4][4] = {};
  for (int k0 = 0; k0 < K_; k0 += 64) {
    __syncthreads();
    #pragma unroll
    for (int p = 0; p < 4; ++p) {
      const int linear = p * 256 + tid;
      const int r = linear >> 3, s = linear & 7;
      const float4 a0 = *(const float4*)&X[(size_t)(m0 + r) * K_ + k0 + s * 8];
      const float4 a1 = *(const float4*)&X[(size_t)(m0 + r) * K_ + k0 + s * 8 + 4];
      const float4 b0 = *(const float4*)&W[(size_t)(n0 + r) * K_ + k0 + s * 8];
      const float4 b1 = *(const float4*)&W[(size_t)(n0 + r) * K_ + k0 + s * 8 + 4];
      const int ph = (s ^ (r & 7)) * 8;
      *(uint4*)&As[r * 64 + ph] = pack8(a0, a1);
      *(uint4*)&Bs[r * 64 + ph] = pack8(b0, b1);
    }
    __syncthreads();
    #pragma unroll
    for (int ks = 0; ks < 64; ks += 32) {
      const int segl = (ks >> 3) + lrow;
      bf16x8 af[4], bfr[4];
      #pragma unroll
      for (int i = 0; i < 4; ++i) {
        const int r = wm + lcol + 16 * i;
        af[i] = *(const bf16x8*)&As[r * 64 + ((segl ^ (r & 7)) * 8)];
      }
      #pragma unroll
      for (int j = 0; j < 4; ++j) {
        const int r = wn + lcol + 16 * j;
        bfr[j] = *(const bf16x8*)&Bs[r * 64 + ((segl ^ (r & 7)) * 8)];
      }
      #pragma unroll
      for (int i = 0; i < 4; ++i)
        #pragma unroll
        for (int j = 0; j < 4; ++j)
          acc[i][j] = __builtin_amdgcn_mfma_f32_16x16x32_bf16(
              af[i], bfr[j], acc[i][j], 0, 0, 0);
    }
  }
  #pragma unroll
  for (int i = 0; i < 4; ++i)
    #pragma unroll
    for (int j = 0; j < 4; ++j)
      #pragma unroll
      for (int r = 0; r < 4; ++r) {
        const int gm = m0 + wm + 16 * i + lrow * 4 + r;
        const int gn = n0 + wn + 16 * j + lcol;
        QKV[(size_t)gm * E_ + gn] = f2bf(acc[i][j][r]);
      }
}

// ---------------------------------------------------------------------------
// Kernel 2 (r13): r5-EXACT attention body (KVBLK=64 restored -- r12's
// KVBLK=128 was neutral-to-worse) with ONE delta: the softmax bf16 convert
// uses the native (__bf16) cast instead of the manual f2bf bit-twiddle.
// f2bf = ~4 VALU ops x 32 calls = ~128 ops sitting SERIALLY between QK^T and
// PV at 2 waves/SIMD; HW v_cvt_pk_bf16_f32 is 1 op and RNE -- bit-identical
// for exp's positive-normal outputs (m240: let the compiler emit cvt).
// Everything else (layouts, strides, XOR keys, staging, setprio) unchanged.
// ---------------------------------------------------------------------------
__global__ __launch_bounds__(256, 2)
void attn(const u16* __restrict__ QKV, float* __restrict__ Out) {
  __shared__ __align__(16) u16 Ks[64 * 72];
  __shared__ __align__(16) u16 Vt[64 * 72];        // XOR-swizzled, stride 72
  __shared__ __align__(16) u16 Ps[4][32 * 72];     // 32 rows per wave

  const int tid = threadIdx.x, wave = tid >> 6, lane = tid & 63;
  const int b = blockIdx.x >> 4, h = blockIdx.x & 15;
  const int i0 = blockIdx.y * 128;
  const int lcol = lane & 15, lrow = lane >> 4;
  const size_t base = (size_t)b * NSEQ;
  const int qoff = h * DH, koff = DIMN + h * DH, voff = 2 * DIMN + h * DH;
  const int sr = tid >> 3;  // 0..31
  const int sg = tid & 7;
  __bf16* const psb = (__bf16*)&Ps[wave][0];

  bf16x8 ones;
  #pragma unroll
  for (int t = 0; t < 8; ++t) ones[t] = (__bf16)1.0f;

  // Q fragments straight from global (once)
  bf16x8 aq[2][2];
  #pragma unroll
  for (int qi = 0; qi < 2; ++qi)
    #pragma unroll
    for (int ksi = 0; ksi < 2; ++ksi) {
      const int row = i0 + wave * 32 + qi * 16 + lcol;
      aq[qi][ksi] = *(const bf16x8*)&QKV[(base + row) * E_ + qoff +
                                         (ksi * 4 + lrow) * 8];
    }

  // prefetch K/V tile 0
  uint4 kreg[2], vreg[2];
  #pragma unroll
  for (int p = 0; p < 2; ++p) {
    const int row = p * 32 + sr;
    const u16* src = &QKV[(base + row) * E_];
    kreg[p] = *(const uint4*)&src[koff + sg * 8];
    vreg[p] = *(const uint4*)&src[voff + sg * 8];
  }

  f32x4 o[2][4] = {};
  f32x4 lacc[2] = {};

  for (int j0 = 0; j0 < NSEQ; j0 += 64) {
    __syncthreads();
    #pragma unroll
    for (int p = 0; p < 2; ++p) {
      const int row = p * 32 + sr;
      *(uint4*)&Ks[row * 72 + sg * 8] = kreg[p];
      const u16* pv = (const u16*)&vreg[p];
      const int jseg = (row >> 3) & 7, jlo = row & 7;
      #pragma unroll
      for (int t = 0; t < 8; ++t)
        Vt[(sg * 8 + t) * 72 + (((jseg ^ sg) & 7) * 8 + jlo)] = pv[t];
    }
    __syncthreads();

    if (j0 + 64 < NSEQ) {
      #pragma unroll
      for (int p = 0; p < 2; ++p) {
        const int row = p * 32 + sr;
        const u16* src = &QKV[(base + j0 + 64 + row) * E_];
        kreg[p] = *(const uint4*)&src[koff + sg * 8];
        vreg[p] = *(const uint4*)&src[voff + sg * 8];
      }
    }

    // S: [2 qi x 16 q] x 64 j — each bk read feeds 2 MFMAs
    f32x4 s[2][4] = {};
    #pragma unroll
    for (int ksi = 0; ksi < 2; ++ksi) {
      const int seg = ksi * 4 + lrow;
      #pragma unroll
      for (int jt = 0; jt < 4; ++jt) {
        const bf16x8 bk = *(const bf16x8*)&Ks[(jt * 16 + lcol) * 72 + seg * 8];
        __builtin_amdgcn_s_setprio(1);
        #pragma unroll
        for (int qi = 0; qi < 2; ++qi)
          s[qi][jt] = __builtin_amdgcn_mfma_f32_16x16x32_bf16(
              aq[qi][ksi], bk, s[qi][jt], 0, 0, 0);
        __builtin_amdgcn_s_setprio(0);
      }
    }

    // static-base softmax numerator -> Ps (A-layout; native bf16 cast: HW
    // v_cvt, 1 op vs f2bf's ~4 -- RNE-identical for exp's positive outputs)
    #pragma unroll
    for (int qi = 0; qi < 2; ++qi)
      #pragma unroll
      for (int jt = 0; jt < 4; ++jt)
        #pragma unroll
        for (int r = 0; r < 4; ++r) {
          const float p = __expf(fmaf(s[qi][jt][r], 0.125f, -12.0f));
          psb[(qi * 16 + lrow * 4 + r) * 72 + jt * 16 + lcol] = (__bf16)p;
        }

    // O += P@V ; l += P@1 — each bv read feeds 2 MFMAs
    #pragma unroll
    for (int ksi = 0; ksi < 2; ++ksi) {
      const int seg = ksi * 4 + lrow;
      bf16x8 ap[2];
      #pragma unroll
      for (int qi = 0; qi < 2; ++qi)
        ap[qi] = *(const bf16x8*)&Ps[wave][(qi * 16 + lcol) * 72 + seg * 8];
      __builtin_amdgcn_s_setprio(1);
      #pragma unroll
      for (int dt = 0; dt < 4; ++dt) {
        const int d = dt * 16 + lcol;
        const bf16x8 bv = *(const bf16x8*)&Vt[d * 72 + (((seg ^ (d >> 3)) & 7) * 8)];
        #pragma unroll
        for (int qi = 0; qi < 2; ++qi)
          o[qi][dt] = __builtin_amdgcn_mfma_f32_16x16x32_bf16(
              ap[qi], bv, o[qi][dt], 0, 0, 0);
      }
      #pragma unroll
      for (int qi = 0; qi < 2; ++qi)
        lacc[qi] = __builtin_amdgcn_mfma_f32_16x16x32_bf16(
            ap[qi], ones, lacc[qi], 0, 0, 0);
      __builtin_amdgcn_s_setprio(0);
    }
  }

  // epilogue: FP32 out[b, n*H + h, d] = o / l
  #pragma unroll
  for (int qi = 0; qi < 2; ++qi)
    #pragma unroll
    for (int r = 0; r < 4; ++r) {
      const float inv = 1.0f / lacc[qi][r];
      const int i = i0 + wave * 32 + qi * 16 + lrow * 4 + r;
      #pragma unroll
      for (int dt = 0; dt < 4; ++dt) {
        const int d = dt * 16 + lcol;
        Out[((base + i) * NH + h) * DH + d] = o[qi][dt][r] * inv;
      }
    }
}

extern "C" void kernel_launch(void* const* d_in, const int* in_sizes, int n_in,
                              void* d_out, int out_size, void* d_ws, size_t ws_size,
                              hipStream_t stream) {
  const float* x = (const float*)d_in[0];   // fp32 (2,2048,1024)
  const float* w = (const float*)d_in[1];   // fp32 (3072,1024)
  u16* qkv = (u16*)d_ws;                    // bf16 scratch (24 MB)
  float* out = (float*)d_out;               // fp32 (2, 2048*16, 64)

  if (ws_size < QKV_BYTES) return;

  if (ws_size >= NEED2) {
    u16* Xb = (u16*)((char*)d_ws + QKV_BYTES);
    u16* Wb = Xb + XB_ELEMS;
    convert_bf16<<<1024, 256, 0, stream>>>(x, w, Xb, Wb);
    qkv_gemm_a<<<dim3(M_ / 128, E_ / 128), 256, 0, stream>>>(Xb, Wb, qkv);
  } else {
    qkv_gemm_f<<<dim3(M_ / 128, E_ / 128), 256, 0, stream>>>(x, w, qkv);
  }
  attn<<<dim3(BATCH * NH, NSEQ / 128), 256, 0, stream>>>(qkv, out);
}